// Round 1
// baseline (16067.946 us; speedup 1.0000x reference)
//
#include <hip/hip_runtime.h>
#include <math.h>

#define B_ 256
#define D_ 564
#define S_ 40
#define NB_ 6
#define N_ 2256          // 4*D
#define M_ 10240         // B*S
#define DD_ 318096       // D*D
#define OUTIN_ 1128

// ---------------------------------------------------------------------------
// 0) transpose inp (B, D, S) -> x (B, S, D)
// ---------------------------------------------------------------------------
__global__ __launch_bounds__(256) void k_transpose(const float* __restrict__ inp,
                                                   float* __restrict__ x) {
    __shared__ float tile[64][41];
    int b  = blockIdx.y;
    int d0 = blockIdx.x * 64;
    const float* ip = inp + (size_t)b * (D_ * S_);
    for (int idx = threadIdx.x; idx < 64 * 40; idx += 256) {
        int i = idx / 40, s = idx - i * 40;
        if (d0 + i < D_) tile[i][s] = ip[(size_t)(d0 + i) * S_ + s];
    }
    __syncthreads();
    float* xp = x + (size_t)b * (D_ * S_);
    for (int idx = threadIdx.x; idx < 40 * 64; idx += 256) {
        int j = idx & 63, s = idx >> 6;
        if (d0 + j < D_) xp[(size_t)s * D_ + d0 + j] = tile[j][s];
    }
}

// ---------------------------------------------------------------------------
// 1) LayerNorm row stats: one wave per row (b,s)
// ---------------------------------------------------------------------------
__global__ __launch_bounds__(256) void k_lnstats(const float* __restrict__ x,
                                                 float* __restrict__ lmu,
                                                 float* __restrict__ lrs) {
    int row  = blockIdx.x * 4 + (threadIdx.x >> 6);
    int lane = threadIdx.x & 63;
    const float* xp = x + (size_t)row * D_;
    float s1 = 0.f, s2 = 0.f;
    for (int i = lane; i < D_; i += 64) {
        float v = xp[i];
        s1 += v;
        s2 += v * v;
    }
    for (int off = 32; off; off >>= 1) {
        s1 += __shfl_down(s1, off);
        s2 += __shfl_down(s2, off);
    }
    if (lane == 0) {
        float mu  = s1 * (1.f / D_);
        float var = fmaxf(s2 * (1.f / D_) - mu * mu, 0.f);
        lmu[row] = mu;
        lrs[row] = rsqrtf(var + 1e-5f);
    }
}

// ---------------------------------------------------------------------------
// 2) pre-GEMM: pre[s][b][n] = sum_k h[m][k] * Wc[k][n] + bg[n]
//    h fused from x + LN stats.  M=10240, N=2256, K=564.
//    BM=128 BN=64 BK=16, 256 threads, 8x4 micro-tile.
// ---------------------------------------------------------------------------
__global__ __launch_bounds__(256) void k_pregemm(const float* __restrict__ x,
                                                 const float* __restrict__ W,   // (4,D,D)
                                                 const float* __restrict__ bgl, // (2256,)
                                                 const float* __restrict__ lg,
                                                 const float* __restrict__ lb,
                                                 const float* __restrict__ lmu,
                                                 const float* __restrict__ lrs,
                                                 float* __restrict__ pre) {
    __shared__ float As[16][132];
    __shared__ float Bs[16][68];
    int tid = threadIdx.x;
    int m0  = blockIdx.x * 128;
    int n0  = blockIdx.y * 64;
    int tx  = tid & 15, ty = tid >> 4;
    float acc[8][4] = {};

    int aq = tid & 3;   // k-quad for A load
    int ai = tid >> 2;  // row 0..63
    int bn = tid & 63;  // col for B load
    int bk = tid >> 6;  // k row 0..3 (step 4)

    for (int k0 = 0; k0 < D_; k0 += 16) {
        int kk   = k0 + aq * 4;
        bool kok = (kk < D_);
        float4 gv = make_float4(0, 0, 0, 0), bv = gv;
        if (kok) {
            gv = *(const float4*)(lg + kk);
            bv = *(const float4*)(lb + kk);
        }
#pragma unroll
        for (int p = 0; p < 2; ++p) {
            int i = ai + p * 64;
            int m = m0 + i;
            float4 v = make_float4(0, 0, 0, 0);
            if (kok) {
                v = *(const float4*)(x + (size_t)m * D_ + kk);
                float mu = lmu[m], rs = lrs[m];
                v.x = (v.x - mu) * rs * gv.x + bv.x;
                v.y = (v.y - mu) * rs * gv.y + bv.y;
                v.z = (v.z - mu) * rs * gv.z + bv.z;
                v.w = (v.w - mu) * rs * gv.w + bv.w;
            }
            As[aq * 4 + 0][i] = v.x;
            As[aq * 4 + 1][i] = v.y;
            As[aq * 4 + 2][i] = v.z;
            As[aq * 4 + 3][i] = v.w;
        }
#pragma unroll
        for (int p = 0; p < 4; ++p) {
            int k = k0 + bk + p * 4;
            int n = n0 + bn;
            float wv = 0.f;
            if (k < D_ && n < N_) {
                int g = n / D_, e = n - g * D_;
                wv = W[(size_t)g * DD_ + (size_t)k * D_ + e];
            }
            Bs[bk + p * 4][bn] = wv;
        }
        __syncthreads();
#pragma unroll
        for (int k = 0; k < 16; ++k) {
            float a[8], bq[4];
            *(float4*)&a[0]  = *(const float4*)&As[k][ty * 8];
            *(float4*)&a[4]  = *(const float4*)&As[k][ty * 8 + 4];
            *(float4*)&bq[0] = *(const float4*)&Bs[k][tx * 4];
#pragma unroll
            for (int r = 0; r < 8; ++r)
#pragma unroll
                for (int c = 0; c < 4; ++c)
                    acc[r][c] = fmaf(a[r], bq[c], acc[r][c]);
        }
        __syncthreads();
    }

    int nbase = n0 + tx * 4;
    if (nbase < N_) {
        float4 bias = *(const float4*)(bgl + nbase);
#pragma unroll
        for (int r = 0; r < 8; ++r) {
            int m  = m0 + ty * 8 + r;
            int bb = m / 40, ss = m - bb * 40;
            float4 o;
            o.x = acc[r][0] + bias.x;
            o.y = acc[r][1] + bias.y;
            o.z = acc[r][2] + bias.z;
            o.w = acc[r][3] + bias.w;
            *(float4*)(pre + ((size_t)ss * B_ + bb) * N_ + nbase) = o;
        }
    }
}

// ---------------------------------------------------------------------------
// 3) one sLSTM time step.  grid (16 e-tiles, 16 b-groups), 576 threads.
//    thread = (b within group [lane&15], e within tile).  4 gate dots of len 564.
// ---------------------------------------------------------------------------
__global__ __launch_bounds__(576) void k_rec_step(int t,
                                                  float* __restrict__ x,
                                                  const float* __restrict__ pre,
                                                  const float* __restrict__ R, // (4,D,D)
                                                  const float* __restrict__ h_in,
                                                  float* __restrict__ h_out,
                                                  float* __restrict__ cS,
                                                  float* __restrict__ nS,
                                                  float* __restrict__ mS) {
    __shared__ float hs[16 * 573];
    int ht    = blockIdx.x;     // e-tile (36 wide)
    int bg    = blockIdx.y;     // b-group (16 wide)
    int tid   = threadIdx.x;
    int b_loc = tid & 15;
    int e_loc = tid >> 4;       // 0..35
    int e     = ht * 36 + e_loc;
    int b     = bg * 16 + b_loc;

    if (t > 0) {
        for (int idx = tid; idx < 16 * D_; idx += 576) {
            int bl = idx / D_;
            hs[bl * 573 + (idx - bl * D_)] = h_in[(size_t)bg * 16 * D_ + idx];
        }
        __syncthreads();
    }

    if (e < D_) {
        size_t cell = (size_t)b * D_ + e;
        const float* prp = pre + (size_t)t * B_ * N_ + (size_t)b * N_ + e;
        float it = prp[0], ft = prp[D_], zt = prp[2 * D_], ot = prp[3 * D_];
        float cv = 0.f, nv = 0.f, mv = 0.f;
        if (t > 0) {
            cv = cS[cell];
            nv = nS[cell];
            mv = mS[cell];
            const float* Rp = R + e;
            const float* hp = &hs[b_loc * 573];
            float a0 = 0.f, a1 = 0.f, a2 = 0.f, a3 = 0.f;
#pragma unroll 4
            for (int d = 0; d < D_; ++d) {
                float hv       = hp[d];
                const float* r = Rp + (size_t)d * D_;
                a0 = fmaf(hv, r[0], a0);
                a1 = fmaf(hv, r[DD_], a1);
                a2 = fmaf(hv, r[2 * DD_], a2);
                a3 = fmaf(hv, r[3 * DD_], a3);
            }
            it += a0; ft += a1; zt += a2; ot += a3;
        }
        float mn = fmaxf(ft + mv, it);
        float iv = __expf(it - mn);
        float fv = __expf(ft + mv - mn);
        float cn = fv * cv + iv * tanhf(zt);
        float nn = fv * nv + iv;
        float hn = (cn / fmaxf(nn, 1e-6f)) / (1.f + __expf(-ot));
        cS[cell] = cn;
        nS[cell] = nn;
        mS[cell] = mn;
        h_out[cell] = hn;
        x[((size_t)b * S_ + t) * D_ + e] += hn;
    }
}

// ---------------------------------------------------------------------------
// 4) BatchNorm stats per channel d  ->  scale/shift
// ---------------------------------------------------------------------------
__global__ __launch_bounds__(256) void k_bnstats(const float* __restrict__ x,
                                                 const float* __restrict__ bn_g,
                                                 const float* __restrict__ bn_b,
                                                 float* __restrict__ sc,
                                                 float* __restrict__ sh) {
    int d = blockIdx.x;
    float s1 = 0.f, s2 = 0.f;
    for (int r = threadIdx.x; r < M_; r += 256) {
        float v = x[(size_t)r * D_ + d];
        s1 += v;
        s2 += v * v;
    }
    __shared__ float r1[256], r2[256];
    r1[threadIdx.x] = s1;
    r2[threadIdx.x] = s2;
    __syncthreads();
    for (int off = 128; off; off >>= 1) {
        if (threadIdx.x < off) {
            r1[threadIdx.x] += r1[threadIdx.x + off];
            r2[threadIdx.x] += r2[threadIdx.x + off];
        }
        __syncthreads();
    }
    if (threadIdx.x == 0) {
        float mu  = r1[0] * (1.f / M_);
        float var = fmaxf(r2[0] * (1.f / M_) - mu * mu, 0.f);
        float s   = bn_g[d] * rsqrtf(var + 1e-5f);
        sc[d] = s;
        sh[d] = bn_b[d] - mu * s;
    }
}

// ---------------------------------------------------------------------------
// 5) final projection + tanh.  one wg per (b,p): dot of length 1128, 2 outputs
// ---------------------------------------------------------------------------
__global__ __launch_bounds__(128) void k_final(const float* __restrict__ x,
                                               const float* __restrict__ sc,
                                               const float* __restrict__ sh,
                                               const float* __restrict__ w6,
                                               const float* __restrict__ b6,
                                               float* __restrict__ out) {
    int b = blockIdx.x / 20;
    int p = blockIdx.x - b * 20;
    float a0 = 0.f, a1 = 0.f;
    for (int q = threadIdx.x; q < OUTIN_; q += 128) {
        int u = p * OUTIN_ + q;
        int d = u / 40, s = u - d * 40;
        float v = x[((size_t)b * S_ + s) * D_ + d] * sc[d] + sh[d];
        a0 = fmaf(v, w6[q * 2 + 0], a0);
        a1 = fmaf(v, w6[q * 2 + 1], a1);
    }
    __shared__ float r0[128], r1[128];
    r0[threadIdx.x] = a0;
    r1[threadIdx.x] = a1;
    __syncthreads();
    for (int off = 64; off; off >>= 1) {
        if (threadIdx.x < off) {
            r0[threadIdx.x] += r0[threadIdx.x + off];
            r1[threadIdx.x] += r1[threadIdx.x + off];
        }
        __syncthreads();
    }
    if (threadIdx.x == 0) {
        out[((size_t)b * 20 + p) * 2 + 0] = tanhf(r0[0] + b6[0]);
        out[((size_t)b * 20 + p) * 2 + 1] = tanhf(r1[0] + b6[1]);
    }
}

// ---------------------------------------------------------------------------
extern "C" void kernel_launch(void* const* d_in, const int* in_sizes, int n_in,
                              void* d_out, int out_size, void* d_ws, size_t ws_size,
                              hipStream_t stream) {
    const float* inp  = (const float*)d_in[0];
    const float* Wg   = (const float*)d_in[1];
    const float* Rg   = (const float*)d_in[2];
    const float* bg   = (const float*)d_in[3];
    const float* ln_g = (const float*)d_in[4];
    const float* ln_b = (const float*)d_in[5];
    const float* bn_g = (const float*)d_in[6];
    const float* bn_b = (const float*)d_in[7];
    const float* w6   = (const float*)d_in[8];
    const float* b6   = (const float*)d_in[9];
    float* out = (float*)d_out;

    const size_t MD = (size_t)M_ * D_;   // 5,775,360
    const size_t MN = (size_t)M_ * N_;   // 23,101,440
    const size_t BD = (size_t)B_ * D_;   // 144,384

    float* w   = (float*)d_ws;
    float* x   = w;  w += MD;
    float* pre = w;  w += MN;
    float* lmu = w;  w += M_;
    float* lrs = w;  w += M_;
    float* cS  = w;  w += BD;
    float* nS  = w;  w += BD;
    float* mS  = w;  w += BD;
    float* hA  = w;  w += BD;
    float* hB  = w;  w += BD;
    float* sc  = w;  w += D_;
    float* sh  = w;  w += D_;

    k_transpose<<<dim3(9, B_), 256, 0, stream>>>(inp, x);

    for (int l = 0; l < NB_; ++l) {
        const float* Wl  = Wg + (size_t)l * 4 * DD_;
        const float* Rl  = Rg + (size_t)l * 4 * DD_;
        const float* bgl = bg + (size_t)l * N_;
        const float* lgl = ln_g + (size_t)l * D_;
        const float* lbl = ln_b + (size_t)l * D_;

        k_lnstats<<<M_ / 4, 256, 0, stream>>>(x, lmu, lrs);
        k_pregemm<<<dim3(80, 36), 256, 0, stream>>>(x, Wl, bgl, lgl, lbl, lmu, lrs, pre);

        for (int t = 0; t < S_; ++t) {
            float* h_out = (t & 1) ? hB : hA;
            float* h_in  = (t & 1) ? hA : hB;
            k_rec_step<<<dim3(16, 16), 576, 0, stream>>>(t, x, pre, Rl, h_in, h_out,
                                                         cS, nS, mS);
        }
    }

    k_bnstats<<<D_, 256, 0, stream>>>(x, bn_g, bn_b, sc, sh);
    k_final<<<B_ * 20, 128, 0, stream>>>(x, sc, sh, w6, b6, out);
}

// Round 2
// 4405.028 us; speedup vs baseline: 3.6476x; 3.6476x over previous
//
#include <hip/hip_runtime.h>
#include <math.h>

#define B_ 256
#define D_ 564
#define S_ 40
#define NB_ 6
#define N_ 2256          // 4*D
#define M_ 10240         // B*S
#define DD_ 318096       // D*D
#define KP_ 576          // D padded to multiple of 32 for MFMA K
#define OUTIN_ 1128

typedef _Float16 f16;
typedef _Float16 f16x8 __attribute__((ext_vector_type(8)));
typedef float    f32x4 __attribute__((ext_vector_type(4)));

// ---------------------------------------------------------------------------
// P) prep: W,R (l,g,k,e) fp32 -> (l,g,e,k) fp16, k padded 564->576 with zeros
// ---------------------------------------------------------------------------
__global__ __launch_bounds__(256) void k_prep(const float* __restrict__ Wg,
                                              const float* __restrict__ Rg,
                                              f16* __restrict__ Wt,
                                              f16* __restrict__ Rt) {
    __shared__ float tile[32][33];
    int bz  = blockIdx.z;            // 0..47
    int sel = bz / 24;               // 0 = W, 1 = R
    int lg  = bz - sel * 24;         // layer*4 + gate
    const float* src = (sel ? Rg : Wg) + (size_t)lg * DD_;
    f16*         dst = (sel ? Rt : Wt) + (size_t)lg * (D_ * KP_);
    int k0 = blockIdx.x * 32, e0 = blockIdx.y * 32;
    int j = threadIdx.x & 31;
    for (int i = threadIdx.x >> 5; i < 32; i += 8) {
        int k = k0 + i, e = e0 + j;
        tile[i][j] = (k < D_ && e < D_) ? src[(size_t)k * D_ + e] : 0.f;
    }
    __syncthreads();
    for (int i = threadIdx.x >> 5; i < 32; i += 8) {
        int e = e0 + i, k = k0 + j;
        if (e < D_ && k < KP_) dst[(size_t)e * KP_ + k] = (f16)tile[j][i];
    }
}

// ---------------------------------------------------------------------------
// 0) transpose inp (B, D, S) -> x (B, S, D)
// ---------------------------------------------------------------------------
__global__ __launch_bounds__(256) void k_transpose(const float* __restrict__ inp,
                                                   float* __restrict__ x) {
    __shared__ float tile[64][41];
    int b  = blockIdx.y;
    int d0 = blockIdx.x * 64;
    const float* ip = inp + (size_t)b * (D_ * S_);
    for (int idx = threadIdx.x; idx < 64 * 40; idx += 256) {
        int i = idx / 40, s = idx - i * 40;
        if (d0 + i < D_) tile[i][s] = ip[(size_t)(d0 + i) * S_ + s];
    }
    __syncthreads();
    float* xp = x + (size_t)b * (D_ * S_);
    for (int idx = threadIdx.x; idx < 40 * 64; idx += 256) {
        int j = idx & 63, s = idx >> 6;
        if (d0 + j < D_) xp[(size_t)s * D_ + d0 + j] = tile[j][s];
    }
}

// ---------------------------------------------------------------------------
// 1) LayerNorm row stats
// ---------------------------------------------------------------------------
__global__ __launch_bounds__(256) void k_lnstats(const float* __restrict__ x,
                                                 float* __restrict__ lmu,
                                                 float* __restrict__ lrs) {
    int row  = blockIdx.x * 4 + (threadIdx.x >> 6);
    int lane = threadIdx.x & 63;
    const float* xp = x + (size_t)row * D_;
    float s1 = 0.f, s2 = 0.f;
    for (int i = lane; i < D_; i += 64) {
        float v = xp[i];
        s1 += v;
        s2 += v * v;
    }
    for (int off = 32; off; off >>= 1) {
        s1 += __shfl_down(s1, off);
        s2 += __shfl_down(s2, off);
    }
    if (lane == 0) {
        float mu  = s1 * (1.f / D_);
        float var = fmaxf(s2 * (1.f / D_) - mu * mu, 0.f);
        lmu[row] = mu;
        lrs[row] = rsqrtf(var + 1e-5f);
    }
}

// ---------------------------------------------------------------------------
// 1b) apply LN + fp16 convert: hA (10240, 576) fp16, pad zeros
// ---------------------------------------------------------------------------
__global__ __launch_bounds__(256) void k_lnapply(const float* __restrict__ x,
                                                 const float* __restrict__ lg,
                                                 const float* __restrict__ lb,
                                                 const float* __restrict__ lmu,
                                                 const float* __restrict__ lrs,
                                                 f16* __restrict__ hA) {
    int idx = blockIdx.x * 256 + threadIdx.x;   // M_*72 slots
    int row = idx / 72, kq = idx - row * 72;
    int k   = kq * 8;
    float mu = lmu[row], rs = lrs[row];
    const float* xp = x + (size_t)row * D_;
    f16x8 o;
    if (kq < 70) {
        float4 v0 = *(const float4*)(xp + k);
        float4 v1 = *(const float4*)(xp + k + 4);
        float4 g0 = *(const float4*)(lg + k);
        float4 g1 = *(const float4*)(lg + k + 4);
        float4 b0 = *(const float4*)(lb + k);
        float4 b1 = *(const float4*)(lb + k + 4);
        o[0] = (f16)((v0.x - mu) * rs * g0.x + b0.x);
        o[1] = (f16)((v0.y - mu) * rs * g0.y + b0.y);
        o[2] = (f16)((v0.z - mu) * rs * g0.z + b0.z);
        o[3] = (f16)((v0.w - mu) * rs * g0.w + b0.w);
        o[4] = (f16)((v1.x - mu) * rs * g1.x + b1.x);
        o[5] = (f16)((v1.y - mu) * rs * g1.y + b1.y);
        o[6] = (f16)((v1.z - mu) * rs * g1.z + b1.z);
        o[7] = (f16)((v1.w - mu) * rs * g1.w + b1.w);
    } else {
#pragma unroll
        for (int j = 0; j < 8; ++j) {
            int kk = k + j;
            float v = (kk < D_) ? (xp[kk] - mu) * rs * lg[kk] + lb[kk] : 0.f;
            o[j] = (f16)v;
        }
    }
    *(f16x8*)(hA + (size_t)row * KP_ + k) = o;
}

// ---------------------------------------------------------------------------
// 2) pre-GEMM (MFMA fp16): pre[m][n] = hA[m][:] @ Wt[n][:] + bg[n]
//    M=10240, N=2256(+pad), K=576.  BM=128 BN=64 BK=32, 256 thr = 4 waves.
// ---------------------------------------------------------------------------
__global__ __launch_bounds__(256) void k_pregemm(const f16* __restrict__ hA,
                                                 const f16* __restrict__ Wt,  // (4,564,576)
                                                 const float* __restrict__ bgl,
                                                 f16* __restrict__ pre) {
    __shared__ __align__(16) f16 As[128 * 40];  // rows padded to 40 halves
    __shared__ __align__(16) f16 Bs[64 * 40];
    int tid  = threadIdx.x;
    int wave = tid >> 6, lane = tid & 63;
    int quad = lane >> 4, l16 = lane & 15;
    int m0 = blockIdx.x * 128;
    int n0 = blockIdx.y * 64;

    // B-load: thread covers (n-col nj, k-chunk kq)
    int nj   = n0 + (tid & 63);
    int kqb  = tid >> 6;                 // 0..3
    bool nok = (nj < N_);
    int njc  = nok ? nj : N_ - 1;
    int gj   = njc / D_, ej = njc - gj * D_;
    const f16* wp = Wt + (size_t)(gj * D_ + ej) * KP_;
    // A-load: thread covers (m-row am, 2 k-chunks ah, ah+2)
    int am = tid & 127, ah = tid >> 7;   // ah 0..1
    const f16* ap = hA + (size_t)(m0 + am) * KP_;

    f32x4 acc[8];
#pragma unroll
    for (int i = 0; i < 8; ++i) acc[i] = (f32x4){0.f, 0.f, 0.f, 0.f};

    for (int k0 = 0; k0 < KP_; k0 += 32) {
        f16x8 av0 = *(const f16x8*)(ap + k0 + ah * 8);
        f16x8 av1 = *(const f16x8*)(ap + k0 + ah * 8 + 16);
        f16x8 bv  = (f16x8){};
        if (nok) bv = *(const f16x8*)(wp + k0 + kqb * 8);
        __syncthreads();
        *(f16x8*)(As + am * 40 + ah * 8)        = av0;
        *(f16x8*)(As + am * 40 + ah * 8 + 16)   = av1;
        *(f16x8*)(Bs + (tid & 63) * 40 + kqb * 8) = bv;
        __syncthreads();
        f16x8 bf = *(const f16x8*)(Bs + (wave * 16 + l16) * 40 + quad * 8);
#pragma unroll
        for (int mt = 0; mt < 8; ++mt) {
            f16x8 af = *(const f16x8*)(As + (mt * 16 + l16) * 40 + quad * 8);
            acc[mt] = __builtin_amdgcn_mfma_f32_16x16x32_f16(af, bf, acc[mt], 0, 0, 0);
        }
    }

    int ncol = n0 + wave * 16 + l16;
    if (ncol < N_) {
        float bias = bgl[ncol];
#pragma unroll
        for (int mt = 0; mt < 8; ++mt)
#pragma unroll
            for (int r = 0; r < 4; ++r) {
                int m = m0 + mt * 16 + quad * 4 + r;
                pre[(size_t)m * N_ + ncol] = (f16)(acc[mt][r] + bias);
            }
    }
}

// ---------------------------------------------------------------------------
// 3) sLSTM step (MFMA fp16): grid (16 et, 16 bg), 576 thr = 9 waves.
//    wave w owns n-16 tile of 144 cols (4 gates x 36 e).  K = 576.
// ---------------------------------------------------------------------------
__global__ __launch_bounds__(576) void k_rec(int t,
                                             const f16* __restrict__ Rt, // (4,564,576)
                                             const f16* __restrict__ pre,
                                             f16* __restrict__ hb,       // (256,576)
                                             float* __restrict__ cS,
                                             float* __restrict__ nS,
                                             float* __restrict__ mS,
                                             float* __restrict__ x) {
    __shared__ __align__(16) float gbuf[144 * 16];
    int tid  = threadIdx.x;
    int et   = blockIdx.x, bg = blockIdx.y;
    int wave = tid >> 6, lane = tid & 63;
    int quad = lane >> 4, l16 = lane & 15;

    if (t > 0) {
        int c = wave * 16 + l16;          // 0..143
        int g = c / 36, el = c - g * 36;
        int e = et * 36 + el;
        int ecl = (e < D_) ? e : D_ - 1;
        const f16* rp = Rt + (size_t)(g * D_ + ecl) * KP_;
        const f16* hp = hb + (size_t)(bg * 16 + l16) * KP_;
        f32x4 acc = (f32x4){0.f, 0.f, 0.f, 0.f};
#pragma unroll
        for (int k0 = 0; k0 < KP_; k0 += 32) {
            f16x8 af = *(const f16x8*)(hp + k0 + quad * 8);
            f16x8 bf = *(const f16x8*)(rp + k0 + quad * 8);
            acc = __builtin_amdgcn_mfma_f32_16x16x32_f16(af, bf, acc, 0, 0, 0);
        }
#pragma unroll
        for (int r = 0; r < 4; ++r) gbuf[c * 16 + quad * 4 + r] = acc[r];
    }
    __syncthreads();

    int b_loc = tid & 15, el2 = tid >> 4;   // el2 0..35
    int e2 = et * 36 + el2;
    int b  = bg * 16 + b_loc;
    if (e2 < D_) {
        float r0 = 0.f, r1 = 0.f, r2 = 0.f, r3 = 0.f;
        float cv = 0.f, nv = 0.f, mv = 0.f;
        size_t cell = (size_t)b * D_ + e2;
        if (t > 0) {
            r0 = gbuf[(0 * 36 + el2) * 16 + b_loc];
            r1 = gbuf[(1 * 36 + el2) * 16 + b_loc];
            r2 = gbuf[(2 * 36 + el2) * 16 + b_loc];
            r3 = gbuf[(3 * 36 + el2) * 16 + b_loc];
            cv = cS[cell];
            nv = nS[cell];
            mv = mS[cell];
        }
        const f16* pp = pre + (size_t)(b * S_ + t) * N_;
        float it = (float)pp[0 * D_ + e2] + r0;
        float ft = (float)pp[1 * D_ + e2] + r1;
        float zt = (float)pp[2 * D_ + e2] + r2;
        float ot = (float)pp[3 * D_ + e2] + r3;
        float mn = fmaxf(ft + mv, it);
        float iv = __expf(it - mn);
        float fv = __expf(ft + mv - mn);
        float cn = fv * cv + iv * tanhf(zt);
        float nn = fv * nv + iv;
        float hn = (cn / fmaxf(nn, 1e-6f)) / (1.f + __expf(-ot));
        cS[cell] = cn;
        nS[cell] = nn;
        mS[cell] = mn;
        hb[(size_t)b * KP_ + e2] = (f16)hn;
        x[(size_t)(b * S_ + t) * D_ + e2] += hn;
    } else {
        hb[(size_t)b * KP_ + e2] = (f16)0.f;   // keep K-pad defined
    }
}

// ---------------------------------------------------------------------------
// 4) BatchNorm: two-phase coalesced reduction
// ---------------------------------------------------------------------------
__global__ __launch_bounds__(256) void k_bnpart(const float* __restrict__ x,
                                                float* __restrict__ part) {
    int r0 = blockIdx.x * 40;
    for (int c = threadIdx.x; c < D_; c += 256) {
        float s1 = 0.f, s2 = 0.f;
        for (int r = 0; r < 40; ++r) {
            float v = x[(size_t)(r0 + r) * D_ + c];
            s1 += v;
            s2 += v * v;
        }
        part[(size_t)blockIdx.x * 1152 + c]       = s1;
        part[(size_t)blockIdx.x * 1152 + 576 + c] = s2;
    }
}

__global__ __launch_bounds__(64) void k_bnfinal(const float* __restrict__ part,
                                                const float* __restrict__ bn_g,
                                                const float* __restrict__ bn_b,
                                                float* __restrict__ sc,
                                                float* __restrict__ sh) {
    int d = blockIdx.x * 64 + threadIdx.x;
    if (d >= D_) return;
    float s1 = 0.f, s2 = 0.f;
    for (int w = 0; w < 256; ++w) {
        s1 += part[(size_t)w * 1152 + d];
        s2 += part[(size_t)w * 1152 + 576 + d];
    }
    float mu  = s1 * (1.f / M_);
    float var = fmaxf(s2 * (1.f / M_) - mu * mu, 0.f);
    float s   = bn_g[d] * rsqrtf(var + 1e-5f);
    sc[d] = s;
    sh[d] = bn_b[d] - mu * s;
}

// ---------------------------------------------------------------------------
// 5) final projection + tanh
// ---------------------------------------------------------------------------
__global__ __launch_bounds__(128) void k_final(const float* __restrict__ x,
                                               const float* __restrict__ sc,
                                               const float* __restrict__ sh,
                                               const float* __restrict__ w6,
                                               const float* __restrict__ b6,
                                               float* __restrict__ out) {
    int b = blockIdx.x / 20;
    int p = blockIdx.x - b * 20;
    float a0 = 0.f, a1 = 0.f;
    for (int q = threadIdx.x; q < OUTIN_; q += 128) {
        int u = p * OUTIN_ + q;
        int d = u / 40, s = u - d * 40;
        float v = x[((size_t)b * S_ + s) * D_ + d] * sc[d] + sh[d];
        a0 = fmaf(v, w6[q * 2 + 0], a0);
        a1 = fmaf(v, w6[q * 2 + 1], a1);
    }
    __shared__ float r0[128], r1[128];
    r0[threadIdx.x] = a0;
    r1[threadIdx.x] = a1;
    __syncthreads();
    for (int off = 64; off; off >>= 1) {
        if (threadIdx.x < off) {
            r0[threadIdx.x] += r0[threadIdx.x + off];
            r1[threadIdx.x] += r1[threadIdx.x + off];
        }
        __syncthreads();
    }
    if (threadIdx.x == 0) {
        out[((size_t)b * 20 + p) * 2 + 0] = tanhf(r0[0] + b6[0]);
        out[((size_t)b * 20 + p) * 2 + 1] = tanhf(r1[0] + b6[1]);
    }
}

// ---------------------------------------------------------------------------
extern "C" void kernel_launch(void* const* d_in, const int* in_sizes, int n_in,
                              void* d_out, int out_size, void* d_ws, size_t ws_size,
                              hipStream_t stream) {
    const float* inp  = (const float*)d_in[0];
    const float* Wg   = (const float*)d_in[1];
    const float* Rg   = (const float*)d_in[2];
    const float* bg   = (const float*)d_in[3];
    const float* ln_g = (const float*)d_in[4];
    const float* ln_b = (const float*)d_in[5];
    const float* bn_g = (const float*)d_in[6];
    const float* bn_b = (const float*)d_in[7];
    const float* w6   = (const float*)d_in[8];
    const float* b6   = (const float*)d_in[9];
    float* out = (float*)d_out;

    float* ws = (float*)d_ws;
    size_t off = 0;
    float* x    = ws + off;        off += (size_t)M_ * D_;        // 5,775,360 f
    f16*   pre  = (f16*)(ws + off); off += (size_t)M_ * N_ / 2;   // fp16
    f16*   hA   = (f16*)(ws + off); off += (size_t)M_ * KP_ / 2;
    f16*   Wt   = (f16*)(ws + off); off += (size_t)NB_ * 4 * D_ * KP_ / 2;
    f16*   Rt   = (f16*)(ws + off); off += (size_t)NB_ * 4 * D_ * KP_ / 2;
    f16*   hb   = (f16*)(ws + off); off += (size_t)B_ * KP_ / 2;
    float* lmu  = ws + off;        off += M_;
    float* lrs  = ws + off;        off += M_;
    float* cS   = ws + off;        off += (size_t)B_ * D_;
    float* nS   = ws + off;        off += (size_t)B_ * D_;
    float* mS   = ws + off;        off += (size_t)B_ * D_;
    float* part = ws + off;        off += 256 * 1152;
    float* sc   = ws + off;        off += 576;
    float* sh   = ws + off;        off += 576;

    k_prep<<<dim3(18, 18, 48), 256, 0, stream>>>(Wg, Rg, Wt, Rt);
    k_transpose<<<dim3(9, B_), 256, 0, stream>>>(inp, x);

    for (int l = 0; l < NB_; ++l) {
        const f16*   Wtl = Wt + (size_t)l * 4 * D_ * KP_;
        const f16*   Rtl = Rt + (size_t)l * 4 * D_ * KP_;
        const float* bgl = bg + (size_t)l * N_;
        const float* lgl = ln_g + (size_t)l * D_;
        const float* lbl = ln_b + (size_t)l * D_;

        k_lnstats<<<M_ / 4, 256, 0, stream>>>(x, lmu, lrs);
        k_lnapply<<<M_ * 72 / 256, 256, 0, stream>>>(x, lgl, lbl, lmu, lrs, hA);
        k_pregemm<<<dim3(80, 36), 256, 0, stream>>>(hA, Wtl, bgl, pre);

        for (int t = 0; t < S_; ++t)
            k_rec<<<dim3(16, 16), 576, 0, stream>>>(t, Rtl, pre, hb, cS, nS, mS, x);
    }

    k_bnpart<<<256, 256, 0, stream>>>(x, part);
    k_bnfinal<<<9, 64, 0, stream>>>(part, bn_g, bn_b, sc, sh);
    k_final<<<B_ * 20, 128, 0, stream>>>(x, sc, sh, w6, b6, out);
}